// Round 11
// baseline (79.747 us; speedup 1.0000x reference)
//
#include <hip/hip_runtime.h>
#include <hip/hip_bf16.h>

// out[q,c] = sum_n exp(-50*r2(q,n)) * d_val[n,c] / (1e-4 + sum_n exp(-50*r2(q,n)))
// Q=16384, N=8192, C=64, f32 in/out.
// MFMA formulation: W (generated bf16) @ V (bf16), f32 accumulate.
// Round 11: TILES=8 (128q x 64c per wave), 128-thread blocks (2 waves),
// grid (64,16) = 1024 blocks = 8 waves/CU = exactly the 2-waves/SIMD reg cap.
// Same 12 VMEM loads/step now feed 4x the original W-gen+MFMA -> half the
// latency events of R10 at identical occupancy. Body otherwise identical.

#define QTOT 16384
#define NTOT 8192
#define CCH  64

typedef __attribute__((ext_vector_type(8))) short bf16x8;
typedef __attribute__((ext_vector_type(4))) float f32x4;
typedef __attribute__((ext_vector_type(4))) int   i32x4;

// exp(-50 r^2) = exp2( q . p' + A_q + B_n ), p' = 144.2695*p, B_n = -72.13474*|p|^2
#define K2F 144.269504089f
#define K1F 72.1347520444f

// ---------- prep: P4[n] = {K2*px, K2*py, K2*pz, -K1*|p|^2} ----------
__global__ __launch_bounds__(256)
void prep_p4(const float* __restrict__ dp, float4* __restrict__ P4) {
    int n = blockIdx.x * 256 + threadIdx.x;
    if (n >= NTOT) return;
    float px = dp[3 * n + 0], py = dp[3 * n + 1], pz = dp[3 * n + 2];
    float4 r;
    r.x = K2F * px; r.y = K2F * py; r.z = K2F * pz;
    r.w = -K1F * (px * px + py * py + pz * pz);
    P4[n] = r;
}

// ---------- prep: Vt[c][n] = bf16(d_val[n][c]) (transposed, bf16) ----------
__global__ __launch_bounds__(256)
void prep_vt(const float* __restrict__ dv, __hip_bfloat16* __restrict__ Vt) {
    int t = blockIdx.x * 256 + threadIdx.x;   // t = c*NTOT + n
    int c = t >> 13;                          // NTOT = 8192
    int n = t & (NTOT - 1);
    Vt[t] = __float2bfloat16(dv[n * CCH + c]);
}

// ---------- main: 2 waves/block; 128 q x 64 c per wave; n-slice in steps of 32 ----------
__global__ __launch_bounds__(128)
void splat_mfma(const float* __restrict__ q_pos,
                const float4* __restrict__ P4,
                const __hip_bfloat16* __restrict__ Vt,   // [64][NTOT]
                float* __restrict__ ws_val,              // [NS][QTOT][64]
                float* __restrict__ ws_w,                // [NS][QTOT]
                int npers)                               // n per slice (mult of 32)
{
    const int wave = threadIdx.x >> 6;
    const int lane = threadIdx.x & 63;
    const int r    = lane & 15;     // A row / B col / C col index
    const int hi   = lane >> 4;     // k-group
    const int qbase = blockIdx.x * 256 + wave * 128;
    const int s  = blockIdx.y;
    const int n0 = s * npers;

    float qx[8], qy[8], qz[8], Aq[8];
#pragma unroll
    for (int t = 0; t < 8; ++t) {
        int q = qbase + t * 16 + r;
        float x = q_pos[3 * q + 0], y = q_pos[3 * q + 1], z = q_pos[3 * q + 2];
        qx[t] = x; qy[t] = y; qz[t] = z;
        Aq[t] = -K1F * (x * x + y * y + z * z);
    }

    f32x4 acc[8][4];
#pragma unroll
    for (int t = 0; t < 8; ++t)
#pragma unroll
        for (int cg = 0; cg < 4; ++cg)
            acc[t][cg] = (f32x4)(0.0f);
    float wsum[8] = {0.f, 0.f, 0.f, 0.f, 0.f, 0.f, 0.f, 0.f};

    for (int nb = n0; nb < n0 + npers; nb += 32) {
        // P4 for this lane's 8 n values (16 lanes per hi-group share -> broadcast)
        float4 p4[8];
        const float4* pp = P4 + nb + 8 * hi;
#pragma unroll
        for (int b = 0; b < 8; ++b) p4[b] = pp[b];

        // B fragments: lane holds V[nb+8*hi+b][cg*16+r] = Vt[cg*16+r][nb+8*hi+b]
        union BF { i32x4 i; bf16x8 v; } bfr[4];
#pragma unroll
        for (int cg = 0; cg < 4; ++cg) {
            const i32x4* bp = (const i32x4*)(Vt + (size_t)(cg * 16 + r) * NTOT + nb + 8 * hi);
            bfr[cg].i = *bp;
        }

        // A fragments: lane holds W[qbase+t*16+r][k=8*hi+b]
        union AF { unsigned u[4]; bf16x8 v; } af[8];
#pragma unroll
        for (int t = 0; t < 8; ++t) {
            float w[8];
#pragma unroll
            for (int b = 0; b < 8; ++b) {
                float bias = p4[b].w + Aq[t];
                float arg = fmaf(qz[t], p4[b].z, fmaf(qy[t], p4[b].y, fmaf(qx[t], p4[b].x, bias)));
                w[b] = __builtin_amdgcn_exp2f(arg);
                wsum[t] += w[b];
            }
#pragma unroll
            for (int d = 0; d < 4; ++d) {
                unsigned u;
                asm("v_cvt_pk_bf16_f32 %0, %1, %2" : "=v"(u) : "v"(w[2 * d]), "v"(w[2 * d + 1]));
                af[t].u[d] = u;
            }
        }

#pragma unroll
        for (int t = 0; t < 8; ++t)
#pragma unroll
            for (int cg = 0; cg < 4; ++cg)
                acc[t][cg] = __builtin_amdgcn_mfma_f32_16x16x32_bf16(af[t].v, bfr[cg].v, acc[t][cg], 0, 0, 0);
    }

    // wsum: lanes with same r hold disjoint n-subsets of the same q -> reduce over hi
#pragma unroll
    for (int t = 0; t < 8; ++t) {
        float wv = wsum[t];
        wv += __shfl_xor(wv, 16);
        wv += __shfl_xor(wv, 32);
        wsum[t] = wv;
    }

    // C layout: col = lane&15 (channel), row = 4*hi + j (q offset)
    float* wsv = ws_val + (size_t)s * QTOT * CCH;
#pragma unroll
    for (int t = 0; t < 8; ++t) {
#pragma unroll
        for (int cg = 0; cg < 4; ++cg)
#pragma unroll
            for (int j = 0; j < 4; ++j) {
                int q = qbase + t * 16 + 4 * hi + j;
                int c = cg * 16 + r;
                wsv[(size_t)q * CCH + c] = acc[t][cg][j];
            }
        if (lane < 16)
            ws_w[(size_t)s * QTOT + qbase + t * 16 + lane] = wsum[t];
    }
}

// ---------- reduce + normalize (float4 vectorized) ----------
__global__ __launch_bounds__(256)
void splat_reduce4(const float4* __restrict__ ws_val,   // [NS][QTOT*16] float4
                   const float* __restrict__ ws_w,
                   float4* __restrict__ out, int NS) {
    int t = blockIdx.x * 256 + threadIdx.x;   // float4 index: q*16 + c4
    int q = t >> 4;
    float4 v = make_float4(0.f, 0.f, 0.f, 0.f);
    float wsum = 0.0f;
    for (int s = 0; s < NS; ++s) {
        float4 a = ws_val[(size_t)s * (QTOT * 16) + t];
        v.x += a.x; v.y += a.y; v.z += a.z; v.w += a.w;
        wsum += ws_w[(size_t)s * QTOT + q];
    }
    float inv = 1.0f / (1e-4f + wsum);
    v.x *= inv; v.y *= inv; v.z *= inv; v.w *= inv;
    out[t] = v;
}

// ---------- fallback: single pass VALU ----------
__global__ __launch_bounds__(256)
void splat_direct(const float* __restrict__ q_pos,
                  const float* __restrict__ d_pos,
                  const float* __restrict__ d_val,
                  float* __restrict__ out, int Q, int N)
{
    const int q = blockIdx.x * blockDim.x + threadIdx.x;
    const float qx = q_pos[q * 3 + 0], qy = q_pos[q * 3 + 1], qz = q_pos[q * 3 + 2];
    float acc[CCH];
#pragma unroll
    for (int c = 0; c < CCH; ++c) acc[c] = 0.0f;
    float wsum = 0.0f;
    for (int n = 0; n < N; ++n) {
        float dx = qx - d_pos[n * 3 + 0];
        float dy = qy - d_pos[n * 3 + 1];
        float dz = qz - d_pos[n * 3 + 2];
        float r2 = fmaf(dx, dx, fmaf(dy, dy, dz * dz));
        float w = __expf(-50.0f * r2);
        wsum += w;
        const float4* row4 = reinterpret_cast<const float4*>(d_val + (size_t)n * CCH);
#pragma unroll
        for (int j = 0; j < CCH / 4; ++j) {
            float4 v = row4[j];
            acc[4 * j + 0] = fmaf(w, v.x, acc[4 * j + 0]);
            acc[4 * j + 1] = fmaf(w, v.y, acc[4 * j + 1]);
            acc[4 * j + 2] = fmaf(w, v.z, acc[4 * j + 2]);
            acc[4 * j + 3] = fmaf(w, v.w, acc[4 * j + 3]);
        }
    }
    float inv = 1.0f / (1e-4f + wsum);
#pragma unroll
    for (int c = 0; c < CCH; ++c) out[(size_t)q * CCH + c] = acc[c] * inv;
}

extern "C" void kernel_launch(void* const* d_in, const int* in_sizes, int n_in,
                              void* d_out, int out_size, void* d_ws, size_t ws_size,
                              hipStream_t stream) {
    const float* q_pos = (const float*)d_in[0];
    const float* d_pos = (const float*)d_in[1];
    const float* d_val = (const float*)d_in[2];
    float* out = (float*)d_out;

    const size_t p4_bytes = (size_t)NTOT * 16;              // 128 KiB
    const size_t vt_bytes = (size_t)NTOT * CCH * 2;         // 1 MiB
    auto need = [&](int ns) {
        return p4_bytes + vt_bytes
             + (size_t)ns * QTOT * CCH * 4 + (size_t)ns * QTOT * 4;
    };

    int NS;
    if (need(16) <= ws_size)      NS = 16;   // 1024 blocks (64 x 16)
    else if (need(8) <= ws_size)  NS = 8;
    else if (need(4) <= ws_size)  NS = 4;
    else {
        splat_direct<<<dim3(QTOT / 256), dim3(256), 0, stream>>>(
            q_pos, d_pos, d_val, out, QTOT, NTOT);
        return;
    }

    float4*          P4 = (float4*)d_ws;
    __hip_bfloat16*  Vt = (__hip_bfloat16*)((char*)d_ws + p4_bytes);
    float*       ws_valp = (float*)((char*)d_ws + p4_bytes + vt_bytes);
    float*         ws_wp = ws_valp + (size_t)NS * QTOT * CCH;

    prep_p4<<<dim3(NTOT / 256), dim3(256), 0, stream>>>(d_pos, P4);
    prep_vt<<<dim3(NTOT * CCH / 256), dim3(256), 0, stream>>>(d_val, Vt);

    splat_mfma<<<dim3(QTOT / 256, NS), dim3(128), 0, stream>>>(
        q_pos, P4, Vt, ws_valp, ws_wp, NTOT / NS);

    splat_reduce4<<<dim3(QTOT * CCH / 4 / 256), dim3(256), 0, stream>>>(
        (const float4*)ws_valp, ws_wp, (float4*)out, NS);
}

// Round 12
// 78.299 us; speedup vs baseline: 1.0185x; 1.0185x over previous
//
#include <hip/hip_runtime.h>
#include <hip/hip_bf16.h>

// out[q,c] = sum_n exp(-50*r2(q,n)) * d_val[n,c] / (1e-4 + sum_n exp(-50*r2(q,n)))
// Q=16384, N=8192, C=64, f32 in/out.
// MFMA formulation: W (generated bf16) @ V (bf16), f32 accumulate.
// Round 12: R10 body byte-identical (TILES=4, 4-wave/256-thread blocks,
// grid 64x16) + ONE change: per-wave phase rotation of the n-step order to
// break the co-resident-wave convoy (both waves stalling on loads at the
// same PC). Sum order changes only across steps -> rounding noise.

#define QTOT 16384
#define NTOT 8192
#define CCH  64

typedef __attribute__((ext_vector_type(8))) short bf16x8;
typedef __attribute__((ext_vector_type(4))) float f32x4;
typedef __attribute__((ext_vector_type(4))) int   i32x4;

// exp(-50 r^2) = exp2( q . p' + A_q + B_n ), p' = 144.2695*p, B_n = -72.13474*|p|^2
#define K2F 144.269504089f
#define K1F 72.1347520444f

// ---------- prep: P4[n] = {K2*px, K2*py, K2*pz, -K1*|p|^2} ----------
__global__ __launch_bounds__(256)
void prep_p4(const float* __restrict__ dp, float4* __restrict__ P4) {
    int n = blockIdx.x * 256 + threadIdx.x;
    if (n >= NTOT) return;
    float px = dp[3 * n + 0], py = dp[3 * n + 1], pz = dp[3 * n + 2];
    float4 r;
    r.x = K2F * px; r.y = K2F * py; r.z = K2F * pz;
    r.w = -K1F * (px * px + py * py + pz * pz);
    P4[n] = r;
}

// ---------- prep: Vt[c][n] = bf16(d_val[n][c]) (transposed, bf16) ----------
__global__ __launch_bounds__(256)
void prep_vt(const float* __restrict__ dv, __hip_bfloat16* __restrict__ Vt) {
    int t = blockIdx.x * 256 + threadIdx.x;   // t = c*NTOT + n
    int c = t >> 13;                          // NTOT = 8192
    int n = t & (NTOT - 1);
    Vt[t] = __float2bfloat16(dv[n * CCH + c]);
}

// ---------- main: 4 waves/block; 64 q x 64 c per wave; phase-rotated n-steps ----------
__global__ __launch_bounds__(256)
void splat_mfma(const float* __restrict__ q_pos,
                const float4* __restrict__ P4,
                const __hip_bfloat16* __restrict__ Vt,   // [64][NTOT]
                float* __restrict__ ws_val,              // [NS][QTOT][64]
                float* __restrict__ ws_w,                // [NS][QTOT]
                int npers)                               // n per slice (mult of 32, pow2)
{
    const int wave = threadIdx.x >> 6;
    const int lane = threadIdx.x & 63;
    const int r    = lane & 15;     // A row / B col / C col index
    const int hi   = lane >> 4;     // k-group
    const int qbase = blockIdx.x * 256 + wave * 64;
    const int s  = blockIdx.y;
    const int n0 = s * npers;

    const int nsteps = npers >> 5;             // power of 2 (16/32/64)
    const int mask   = nsteps - 1;
    const int phase  = (wave * (nsteps >> 2) + blockIdx.x) & mask;  // wave-uniform stagger

    float qx[4], qy[4], qz[4], Aq[4];
#pragma unroll
    for (int t = 0; t < 4; ++t) {
        int q = qbase + t * 16 + r;
        float x = q_pos[3 * q + 0], y = q_pos[3 * q + 1], z = q_pos[3 * q + 2];
        qx[t] = x; qy[t] = y; qz[t] = z;
        Aq[t] = -K1F * (x * x + y * y + z * z);
    }

    f32x4 acc[4][4];
#pragma unroll
    for (int t = 0; t < 4; ++t)
#pragma unroll
        for (int cg = 0; cg < 4; ++cg)
            acc[t][cg] = (f32x4)(0.0f);
    float wsum[4] = {0.0f, 0.0f, 0.0f, 0.0f};

    for (int i = 0; i < nsteps; ++i) {
        const int nb = n0 + (((i + phase) & mask) << 5);

        // P4 for this lane's 8 n values (16 lanes per hi-group share -> broadcast)
        float4 p4[8];
        const float4* pp = P4 + nb + 8 * hi;
#pragma unroll
        for (int b = 0; b < 8; ++b) p4[b] = pp[b];

        // B fragments: lane holds V[nb+8*hi+b][cg*16+r] = Vt[cg*16+r][nb+8*hi+b]
        union BF { i32x4 i; bf16x8 v; } bfr[4];
#pragma unroll
        for (int cg = 0; cg < 4; ++cg) {
            const i32x4* bp = (const i32x4*)(Vt + (size_t)(cg * 16 + r) * NTOT + nb + 8 * hi);
            bfr[cg].i = *bp;
        }

        // A fragments: lane holds W[qbase+t*16+r][k=8*hi+b]
        union AF { unsigned u[4]; bf16x8 v; } af[4];
#pragma unroll
        for (int t = 0; t < 4; ++t) {
            float w[8];
#pragma unroll
            for (int b = 0; b < 8; ++b) {
                float bias = p4[b].w + Aq[t];
                float arg = fmaf(qz[t], p4[b].z, fmaf(qy[t], p4[b].y, fmaf(qx[t], p4[b].x, bias)));
                w[b] = __builtin_amdgcn_exp2f(arg);
                wsum[t] += w[b];
            }
#pragma unroll
            for (int d = 0; d < 4; ++d) {
                unsigned u;
                asm("v_cvt_pk_bf16_f32 %0, %1, %2" : "=v"(u) : "v"(w[2 * d]), "v"(w[2 * d + 1]));
                af[t].u[d] = u;
            }
        }

#pragma unroll
        for (int t = 0; t < 4; ++t)
#pragma unroll
            for (int cg = 0; cg < 4; ++cg)
                acc[t][cg] = __builtin_amdgcn_mfma_f32_16x16x32_bf16(af[t].v, bfr[cg].v, acc[t][cg], 0, 0, 0);
    }

    // wsum: lanes with same r hold disjoint n-subsets of the same q -> reduce over hi
#pragma unroll
    for (int t = 0; t < 4; ++t) {
        float wv = wsum[t];
        wv += __shfl_xor(wv, 16);
        wv += __shfl_xor(wv, 32);
        wsum[t] = wv;
    }

    // C layout: col = lane&15 (channel), row = 4*hi + j (q offset)
    float* wsv = ws_val + (size_t)s * QTOT * CCH;
#pragma unroll
    for (int t = 0; t < 4; ++t) {
#pragma unroll
        for (int cg = 0; cg < 4; ++cg)
#pragma unroll
            for (int j = 0; j < 4; ++j) {
                int q = qbase + t * 16 + 4 * hi + j;
                int c = cg * 16 + r;
                wsv[(size_t)q * CCH + c] = acc[t][cg][j];
            }
        if (lane < 16)
            ws_w[(size_t)s * QTOT + qbase + t * 16 + lane] = wsum[t];
    }
}

// ---------- reduce + normalize (float4 vectorized) ----------
__global__ __launch_bounds__(256)
void splat_reduce4(const float4* __restrict__ ws_val,   // [NS][QTOT*16] float4
                   const float* __restrict__ ws_w,
                   float4* __restrict__ out, int NS) {
    int t = blockIdx.x * 256 + threadIdx.x;   // float4 index: q*16 + c4
    int q = t >> 4;
    float4 v = make_float4(0.f, 0.f, 0.f, 0.f);
    float wsum = 0.0f;
    for (int s = 0; s < NS; ++s) {
        float4 a = ws_val[(size_t)s * (QTOT * 16) + t];
        v.x += a.x; v.y += a.y; v.z += a.z; v.w += a.w;
        wsum += ws_w[(size_t)s * QTOT + q];
    }
    float inv = 1.0f / (1e-4f + wsum);
    v.x *= inv; v.y *= inv; v.z *= inv; v.w *= inv;
    out[t] = v;
}

// ---------- fallback: single pass VALU ----------
__global__ __launch_bounds__(256)
void splat_direct(const float* __restrict__ q_pos,
                  const float* __restrict__ d_pos,
                  const float* __restrict__ d_val,
                  float* __restrict__ out, int Q, int N)
{
    const int q = blockIdx.x * blockDim.x + threadIdx.x;
    const float qx = q_pos[q * 3 + 0], qy = q_pos[q * 3 + 1], qz = q_pos[q * 3 + 2];
    float acc[CCH];
#pragma unroll
    for (int c = 0; c < CCH; ++c) acc[c] = 0.0f;
    float wsum = 0.0f;
    for (int n = 0; n < N; ++n) {
        float dx = qx - d_pos[n * 3 + 0];
        float dy = qy - d_pos[n * 3 + 1];
        float dz = qz - d_pos[n * 3 + 2];
        float r2 = fmaf(dx, dx, fmaf(dy, dy, dz * dz));
        float w = __expf(-50.0f * r2);
        wsum += w;
        const float4* row4 = reinterpret_cast<const float4*>(d_val + (size_t)n * CCH);
#pragma unroll
        for (int j = 0; j < CCH / 4; ++j) {
            float4 v = row4[j];
            acc[4 * j + 0] = fmaf(w, v.x, acc[4 * j + 0]);
            acc[4 * j + 1] = fmaf(w, v.y, acc[4 * j + 1]);
            acc[4 * j + 2] = fmaf(w, v.z, acc[4 * j + 2]);
            acc[4 * j + 3] = fmaf(w, v.w, acc[4 * j + 3]);
        }
    }
    float inv = 1.0f / (1e-4f + wsum);
#pragma unroll
    for (int c = 0; c < CCH; ++c) out[(size_t)q * CCH + c] = acc[c] * inv;
}

extern "C" void kernel_launch(void* const* d_in, const int* in_sizes, int n_in,
                              void* d_out, int out_size, void* d_ws, size_t ws_size,
                              hipStream_t stream) {
    const float* q_pos = (const float*)d_in[0];
    const float* d_pos = (const float*)d_in[1];
    const float* d_val = (const float*)d_in[2];
    float* out = (float*)d_out;

    const size_t p4_bytes = (size_t)NTOT * 16;              // 128 KiB
    const size_t vt_bytes = (size_t)NTOT * CCH * 2;         // 1 MiB
    auto need = [&](int ns) {
        return p4_bytes + vt_bytes
             + (size_t)ns * QTOT * CCH * 4 + (size_t)ns * QTOT * 4;
    };

    int NS;
    if (need(16) <= ws_size)      NS = 16;   // 1024 blocks = 4/CU
    else if (need(8) <= ws_size)  NS = 8;
    else if (need(4) <= ws_size)  NS = 4;
    else {
        splat_direct<<<dim3(QTOT / 256), dim3(256), 0, stream>>>(
            q_pos, d_pos, d_val, out, QTOT, NTOT);
        return;
    }

    float4*          P4 = (float4*)d_ws;
    __hip_bfloat16*  Vt = (__hip_bfloat16*)((char*)d_ws + p4_bytes);
    float*       ws_valp = (float*)((char*)d_ws + p4_bytes + vt_bytes);
    float*         ws_wp = ws_valp + (size_t)NS * QTOT * CCH;

    prep_p4<<<dim3(NTOT / 256), dim3(256), 0, stream>>>(d_pos, P4);
    prep_vt<<<dim3(NTOT * CCH / 256), dim3(256), 0, stream>>>(d_val, Vt);

    splat_mfma<<<dim3(QTOT / 256, NS), dim3(256), 0, stream>>>(
        q_pos, P4, Vt, ws_valp, ws_wp, NTOT / NS);

    splat_reduce4<<<dim3(QTOT * CCH / 4 / 256), dim3(256), 0, stream>>>(
        (const float4*)ws_valp, ws_wp, (float4*)out, NS);
}

// Round 14
// 71.577 us; speedup vs baseline: 1.1141x; 1.0939x over previous
//
#include <hip/hip_runtime.h>
#include <hip/hip_bf16.h>

// out[q,c] = sum_n exp(-50*r2(q,n)) * d_val[n,c] / (1e-4 + sum_n exp(-50*r2(q,n)))
// Q=16384, N=8192, C=64, f32 in/out.
// MFMA formulation: W (generated bf16) @ V (bf16), f32 accumulate.
// Round 14: R10 main-kernel body BYTE-IDENTICAL (proven 4x). Parameter-only
// change: NS=8 (was 16) -> halves partial-write traffic (main epilogue) and
// reduce-pass read traffic; 512 blocks x 4 waves = 2048 waves = exact 2/SIMD
// register cap (96 VGPR + 64 AGPR = 160 regs -> 2 waves/SIMD quantum).
// NOTE (hard-won): any source-level restructure of the inner loop's memory
// schedule (load hoisting, double-buffering, LDS staging, global_load_lds)
// miscompiles on this body -- R3/R5/R6/R7/R13 all garbled. Parameter changes
// only.

#define QTOT 16384
#define NTOT 8192
#define CCH  64

typedef __attribute__((ext_vector_type(8))) short bf16x8;
typedef __attribute__((ext_vector_type(4))) float f32x4;
typedef __attribute__((ext_vector_type(4))) int   i32x4;

// exp(-50 r^2) = exp2( q . p' + A_q + B_n ), p' = 144.2695*p, B_n = -72.13474*|p|^2
#define K2F 144.269504089f
#define K1F 72.1347520444f

// ---------- prep: P4[n] = {K2*px, K2*py, K2*pz, -K1*|p|^2} ----------
__global__ __launch_bounds__(256)
void prep_p4(const float* __restrict__ dp, float4* __restrict__ P4) {
    int n = blockIdx.x * 256 + threadIdx.x;
    if (n >= NTOT) return;
    float px = dp[3 * n + 0], py = dp[3 * n + 1], pz = dp[3 * n + 2];
    float4 r;
    r.x = K2F * px; r.y = K2F * py; r.z = K2F * pz;
    r.w = -K1F * (px * px + py * py + pz * pz);
    P4[n] = r;
}

// ---------- prep: Vt[c][n] = bf16(d_val[n][c]) (transposed, bf16) ----------
__global__ __launch_bounds__(256)
void prep_vt(const float* __restrict__ dv, __hip_bfloat16* __restrict__ Vt) {
    int t = blockIdx.x * 256 + threadIdx.x;   // t = c*NTOT + n
    int c = t >> 13;                          // NTOT = 8192
    int n = t & (NTOT - 1);
    Vt[t] = __float2bfloat16(dv[n * CCH + c]);
}

// ---------- main: 4 waves/block; 64 q x 64 c per wave; n-slice in steps of 32 ----------
__global__ __launch_bounds__(256)
void splat_mfma(const float* __restrict__ q_pos,
                const float4* __restrict__ P4,
                const __hip_bfloat16* __restrict__ Vt,   // [64][NTOT]
                float* __restrict__ ws_val,              // [NS][QTOT][64]
                float* __restrict__ ws_w,                // [NS][QTOT]
                int npers)                               // n per slice (mult of 32)
{
    const int wave = threadIdx.x >> 6;
    const int lane = threadIdx.x & 63;
    const int r    = lane & 15;     // A row / B col / C col index
    const int hi   = lane >> 4;     // k-group
    const int qbase = blockIdx.x * 256 + wave * 64;
    const int s  = blockIdx.y;
    const int n0 = s * npers;

    float qx[4], qy[4], qz[4], Aq[4];
#pragma unroll
    for (int t = 0; t < 4; ++t) {
        int q = qbase + t * 16 + r;
        float x = q_pos[3 * q + 0], y = q_pos[3 * q + 1], z = q_pos[3 * q + 2];
        qx[t] = x; qy[t] = y; qz[t] = z;
        Aq[t] = -K1F * (x * x + y * y + z * z);
    }

    f32x4 acc[4][4];
#pragma unroll
    for (int t = 0; t < 4; ++t)
#pragma unroll
        for (int cg = 0; cg < 4; ++cg)
            acc[t][cg] = (f32x4)(0.0f);
    float wsum[4] = {0.0f, 0.0f, 0.0f, 0.0f};

    for (int nb = n0; nb < n0 + npers; nb += 32) {
        // P4 for this lane's 8 n values (16 lanes per hi-group share -> broadcast)
        float4 p4[8];
        const float4* pp = P4 + nb + 8 * hi;
#pragma unroll
        for (int b = 0; b < 8; ++b) p4[b] = pp[b];

        // B fragments: lane holds V[nb+8*hi+b][cg*16+r] = Vt[cg*16+r][nb+8*hi+b]
        union BF { i32x4 i; bf16x8 v; } bfr[4];
#pragma unroll
        for (int cg = 0; cg < 4; ++cg) {
            const i32x4* bp = (const i32x4*)(Vt + (size_t)(cg * 16 + r) * NTOT + nb + 8 * hi);
            bfr[cg].i = *bp;
        }

        // A fragments: lane holds W[qbase+t*16+r][k=8*hi+b]
        union AF { unsigned u[4]; bf16x8 v; } af[4];
#pragma unroll
        for (int t = 0; t < 4; ++t) {
            float w[8];
#pragma unroll
            for (int b = 0; b < 8; ++b) {
                float bias = p4[b].w + Aq[t];
                float arg = fmaf(qz[t], p4[b].z, fmaf(qy[t], p4[b].y, fmaf(qx[t], p4[b].x, bias)));
                w[b] = __builtin_amdgcn_exp2f(arg);
                wsum[t] += w[b];
            }
#pragma unroll
            for (int d = 0; d < 4; ++d) {
                unsigned u;
                asm("v_cvt_pk_bf16_f32 %0, %1, %2" : "=v"(u) : "v"(w[2 * d]), "v"(w[2 * d + 1]));
                af[t].u[d] = u;
            }
        }

#pragma unroll
        for (int t = 0; t < 4; ++t)
#pragma unroll
            for (int cg = 0; cg < 4; ++cg)
                acc[t][cg] = __builtin_amdgcn_mfma_f32_16x16x32_bf16(af[t].v, bfr[cg].v, acc[t][cg], 0, 0, 0);
    }

    // wsum: lanes with same r hold disjoint n-subsets of the same q -> reduce over hi
#pragma unroll
    for (int t = 0; t < 4; ++t) {
        float wv = wsum[t];
        wv += __shfl_xor(wv, 16);
        wv += __shfl_xor(wv, 32);
        wsum[t] = wv;
    }

    // C layout: col = lane&15 (channel), row = 4*hi + j (q offset)
    float* wsv = ws_val + (size_t)s * QTOT * CCH;
#pragma unroll
    for (int t = 0; t < 4; ++t) {
#pragma unroll
        for (int cg = 0; cg < 4; ++cg)
#pragma unroll
            for (int j = 0; j < 4; ++j) {
                int q = qbase + t * 16 + 4 * hi + j;
                int c = cg * 16 + r;
                wsv[(size_t)q * CCH + c] = acc[t][cg][j];
            }
        if (lane < 16)
            ws_w[(size_t)s * QTOT + qbase + t * 16 + lane] = wsum[t];
    }
}

// ---------- reduce + normalize (float4 vectorized) ----------
__global__ __launch_bounds__(256)
void splat_reduce4(const float4* __restrict__ ws_val,   // [NS][QTOT*16] float4
                   const float* __restrict__ ws_w,
                   float4* __restrict__ out, int NS) {
    int t = blockIdx.x * 256 + threadIdx.x;   // float4 index: q*16 + c4
    int q = t >> 4;
    float4 v = make_float4(0.f, 0.f, 0.f, 0.f);
    float wsum = 0.0f;
    for (int s = 0; s < NS; ++s) {
        float4 a = ws_val[(size_t)s * (QTOT * 16) + t];
        v.x += a.x; v.y += a.y; v.z += a.z; v.w += a.w;
        wsum += ws_w[(size_t)s * QTOT + q];
    }
    float inv = 1.0f / (1e-4f + wsum);
    v.x *= inv; v.y *= inv; v.z *= inv; v.w *= inv;
    out[t] = v;
}

// ---------- fallback: single pass VALU ----------
__global__ __launch_bounds__(256)
void splat_direct(const float* __restrict__ q_pos,
                  const float* __restrict__ d_pos,
                  const float* __restrict__ d_val,
                  float* __restrict__ out, int Q, int N)
{
    const int q = blockIdx.x * blockDim.x + threadIdx.x;
    const float qx = q_pos[q * 3 + 0], qy = q_pos[q * 3 + 1], qz = q_pos[q * 3 + 2];
    float acc[CCH];
#pragma unroll
    for (int c = 0; c < CCH; ++c) acc[c] = 0.0f;
    float wsum = 0.0f;
    for (int n = 0; n < N; ++n) {
        float dx = qx - d_pos[n * 3 + 0];
        float dy = qy - d_pos[n * 3 + 1];
        float dz = qz - d_pos[n * 3 + 2];
        float r2 = fmaf(dx, dx, fmaf(dy, dy, dz * dz));
        float w = __expf(-50.0f * r2);
        wsum += w;
        const float4* row4 = reinterpret_cast<const float4*>(d_val + (size_t)n * CCH);
#pragma unroll
        for (int j = 0; j < CCH / 4; ++j) {
            float4 v = row4[j];
            acc[4 * j + 0] = fmaf(w, v.x, acc[4 * j + 0]);
            acc[4 * j + 1] = fmaf(w, v.y, acc[4 * j + 1]);
            acc[4 * j + 2] = fmaf(w, v.z, acc[4 * j + 2]);
            acc[4 * j + 3] = fmaf(w, v.w, acc[4 * j + 3]);
        }
    }
    float inv = 1.0f / (1e-4f + wsum);
#pragma unroll
    for (int c = 0; c < CCH; ++c) out[(size_t)q * CCH + c] = acc[c] * inv;
}

extern "C" void kernel_launch(void* const* d_in, const int* in_sizes, int n_in,
                              void* d_out, int out_size, void* d_ws, size_t ws_size,
                              hipStream_t stream) {
    const float* q_pos = (const float*)d_in[0];
    const float* d_pos = (const float*)d_in[1];
    const float* d_val = (const float*)d_in[2];
    float* out = (float*)d_out;

    const size_t p4_bytes = (size_t)NTOT * 16;              // 128 KiB
    const size_t vt_bytes = (size_t)NTOT * CCH * 2;         // 1 MiB
    auto need = [&](int ns) {
        return p4_bytes + vt_bytes
             + (size_t)ns * QTOT * CCH * 4 + (size_t)ns * QTOT * 4;
    };

    int NS;
    if (need(8) <= ws_size)       NS = 8;    // 512 blocks = 2048 waves = exact reg-cap fill
    else if (need(4) <= ws_size)  NS = 4;
    else {
        splat_direct<<<dim3(QTOT / 256), dim3(256), 0, stream>>>(
            q_pos, d_pos, d_val, out, QTOT, NTOT);
        return;
    }

    float4*          P4 = (float4*)d_ws;
    __hip_bfloat16*  Vt = (__hip_bfloat16*)((char*)d_ws + p4_bytes);
    float*       ws_valp = (float*)((char*)d_ws + p4_bytes + vt_bytes);
    float*         ws_wp = ws_valp + (size_t)NS * QTOT * CCH;

    prep_p4<<<dim3(NTOT / 256), dim3(256), 0, stream>>>(d_pos, P4);
    prep_vt<<<dim3(NTOT * CCH / 256), dim3(256), 0, stream>>>(d_val, Vt);

    splat_mfma<<<dim3(QTOT / 256, NS), dim3(256), 0, stream>>>(
        q_pos, P4, Vt, ws_valp, ws_wp, NTOT / NS);

    splat_reduce4<<<dim3(QTOT * CCH / 4 / 256), dim3(256), 0, stream>>>(
        (const float4*)ws_valp, ws_wp, (float4*)out, NS);
}